// Round 14
// baseline (367.498 us; speedup 1.0000x reference)
//
#include <hip/hip_runtime.h>

typedef unsigned short u16;
typedef __bf16 bf16x8 __attribute__((ext_vector_type(8)));
typedef float f32x4 __attribute__((ext_vector_type(4)));

#define D_MODEL 1024
#define NHEAD 16
#define DHEAD 64
#define BATCH 8
#define SEQ 1024
#define NROW 8192   // BATCH*SEQ

// ---------- helpers ----------
__device__ __forceinline__ u16 f2bf(float f) {
  union { float f; unsigned int u; } a; a.f = f;
  unsigned int u = a.u;
  return (u16)((u + 0x7fffu + ((u >> 16) & 1u)) >> 16);
}

__device__ __forceinline__ float bf2f(u16 b) {
  union { unsigned int u; float f; } a; a.u = ((unsigned int)b) << 16;
  return a.f;
}

// gelu_tanh(x) == x * sigmoid(2*c*(x+0.044715x^3)); single v_exp_f32, NaN-safe.
__device__ __forceinline__ float gelu_f(float x) {
  float y = 0.79788456080286535588f * (x + 0.044715f * x * x * x);
  return x / (1.0f + __expf(-2.0f * y));
}

__device__ __forceinline__ void async16(const void* gsrc, void* ldst) {
  __builtin_amdgcn_global_load_lds((__attribute__((address_space(1))) void*)gsrc,
                                   (__attribute__((address_space(3))) void*)ldst,
                                   16, 0, 0);
}

// ---------- 4x weight fp32 [1024,1024] -> bf16 W^T, z-indexed ----------
__global__ __launch_bounds__(256)
void wconv4_kernel(const float* __restrict__ Wa, const float* __restrict__ Wb,
                   const float* __restrict__ Wc, const float* __restrict__ Wd,
                   u16* __restrict__ WT) {
  const float* Ws[4] = {Wa, Wb, Wc, Wd};
  const float* W = Ws[blockIdx.z];
  u16* dst = WT + (size_t)blockIdx.z * 1024 * 1024;
  __shared__ float tile[32][33];
  const int tx = threadIdx.x & 31, ty = threadIdx.x >> 5;
  const int n0 = blockIdx.x * 32, k0 = blockIdx.y * 32;
#pragma unroll
  for (int r = 0; r < 4; ++r)
    tile[ty + r * 8][tx] = W[(size_t)(k0 + ty + r * 8) * 1024 + n0 + tx];
  __syncthreads();
#pragma unroll
  for (int r = 0; r < 4; ++r)
    dst[(size_t)(n0 + ty + r * 8) * 1024 + k0 + tx] = f2bf(tile[tx][ty + r * 8]);
}

// ---------- weight fp32 [K,N] -> bf16 W^T [N,K] ----------
__global__ __launch_bounds__(256)
void wconv_kernel(const float* __restrict__ W, u16* __restrict__ WT, int K, int N) {
  __shared__ float tile[32][33];
  const int tx = threadIdx.x & 31, ty = threadIdx.x >> 5;
  const int n0 = blockIdx.x * 32, k0 = blockIdx.y * 32;
#pragma unroll
  for (int r = 0; r < 4; ++r)
    tile[ty + r * 8][tx] = W[(size_t)(k0 + ty + r * 8) * N + n0 + tx];
  __syncthreads();
#pragma unroll
  for (int r = 0; r < 4; ++r)
    WT[(size_t)(n0 + ty + r * 8) * K + k0 + tx] = f2bf(tile[tx][ty + r * 8]);
}

// ---------- layernorm fp32 -> bf16 ----------
__global__ __launch_bounds__(256)
void ln_kernel(const float* __restrict__ x, const float* __restrict__ gamma,
               const float* __restrict__ beta, u16* __restrict__ out) {
  const int row = blockIdx.x, t = threadIdx.x;
  const float4 v = ((const float4*)(x + (size_t)row * D_MODEL))[t];
  float s  = v.x + v.y + v.z + v.w;
  float s2 = v.x * v.x + v.y * v.y + v.z * v.z + v.w * v.w;
#pragma unroll
  for (int off = 32; off >= 1; off >>= 1) {
    s  += __shfl_down(s, off);
    s2 += __shfl_down(s2, off);
  }
  __shared__ float red[8];
  const int w = t >> 6, l = t & 63;
  if (l == 0) { red[w] = s; red[4 + w] = s2; }
  __syncthreads();
  s  = red[0] + red[1] + red[2] + red[3];
  s2 = red[4] + red[5] + red[6] + red[7];
  const float mean = s * (1.0f / D_MODEL);
  const float var  = s2 * (1.0f / D_MODEL) - mean * mean;
  const float inv  = rsqrtf(var + 1e-5f);
  const float4 ga = ((const float4*)gamma)[t];
  const float4 be = ((const float4*)beta)[t];
  ushort4 ov;
  ov.x = f2bf((v.x - mean) * inv * ga.x + be.x);
  ov.y = f2bf((v.y - mean) * inv * ga.y + be.y);
  ov.z = f2bf((v.z - mean) * inv * ga.z + be.z);
  ov.w = f2bf((v.w - mean) * inv * ga.w + be.w);
  ((ushort4*)out)[(size_t)row * 256 + t] = ov;
}

// ---------- layernorm bf16 -> bf16 ----------
__global__ __launch_bounds__(256)
void ln_bf16_kernel(const u16* __restrict__ x, const float* __restrict__ gamma,
                    const float* __restrict__ beta, u16* __restrict__ out) {
  const int row = blockIdx.x, t = threadIdx.x;
  const ushort4 bv = ((const ushort4*)(x + (size_t)row * D_MODEL))[t];
  float4 v;
  v.x = bf2f(bv.x); v.y = bf2f(bv.y); v.z = bf2f(bv.z); v.w = bf2f(bv.w);
  float s  = v.x + v.y + v.z + v.w;
  float s2 = v.x * v.x + v.y * v.y + v.z * v.z + v.w * v.w;
#pragma unroll
  for (int off = 32; off >= 1; off >>= 1) {
    s  += __shfl_down(s, off);
    s2 += __shfl_down(s2, off);
  }
  __shared__ float red[8];
  const int w = t >> 6, l = t & 63;
  if (l == 0) { red[w] = s; red[4 + w] = s2; }
  __syncthreads();
  s  = red[0] + red[1] + red[2] + red[3];
  s2 = red[4] + red[5] + red[6] + red[7];
  const float mean = s * (1.0f / D_MODEL);
  const float var  = s2 * (1.0f / D_MODEL) - mean * mean;
  const float inv  = rsqrtf(var + 1e-5f);
  const float4 ga = ((const float4*)gamma)[t];
  const float4 be = ((const float4*)beta)[t];
  ushort4 ov;
  ov.x = f2bf((v.x - mean) * inv * ga.x + be.x);
  ov.y = f2bf((v.y - mean) * inv * ga.y + be.y);
  ov.z = f2bf((v.z - mean) * inv * ga.z + be.z);
  ov.w = f2bf((v.w - mean) * inv * ga.w + be.w);
  ((ushort4*)out)[(size_t)row * 256 + t] = ov;
}

#define MODE_QK 0
#define MODE_VT 1
#define MODE_YRES 2   // bf16 y = v + bias + f32 resid
#define MODE_GELU 3
#define MODE_OUT 4    // f32 out = v + bias + bf16 resid

// ---------- epilogue for 128^2-tile GEMM ----------
template <int MODE>
__device__ __forceinline__ void gemm_epilogue(f32x4 (&acc)[4][4], int bm, int bn,
                                              int wr, int wc, int c, int g,
                                              const float* bias, const float* resid,
                                              void* outp, int N) {
#pragma unroll
  for (int m = 0; m < 4; ++m) {
    const int r0 = bm * 128 + wr * 64 + m * 16 + g * 4;
#pragma unroll
    for (int n = 0; n < 4; ++n) {
      const int cc = bn * 128 + wc * 64 + n * 16 + c;
#pragma unroll
      for (int i = 0; i < 4; ++i) {
        const int r = r0 + i;
        const float v = acc[m][n][i];
        if constexpr (MODE == MODE_QK) {
          ((u16*)outp)[(((size_t)(r >> 10) * NHEAD + (cc >> 6)) * SEQ + (r & 1023)) * DHEAD + (cc & 63)] = f2bf(v);
        } else if constexpr (MODE == MODE_VT) {
          ((u16*)outp)[(((size_t)(r >> 10) * NHEAD + (cc >> 6)) * DHEAD + (cc & 63)) * SEQ + (r & 1023)] = f2bf(v);
        } else if constexpr (MODE == MODE_YRES) {
          const size_t idx = (size_t)r * N + cc;
          ((u16*)outp)[idx] = f2bf(v + bias[cc] + resid[idx]);
        } else if constexpr (MODE == MODE_OUT) {
          const size_t idx = (size_t)r * N + cc;
          ((float*)outp)[idx] = v + bias[cc] + bf2f(((const u16*)resid)[idx]);
        } else {
          const size_t idx = (size_t)r * N + cc;
          ((u16*)outp)[idx] = f2bf(gelu_f(v + bias[cc]));
        }
      }
    }
  }
}

// ---------- 2-phase GEMM, 128^2 tile, BK=32, 4 blk/CU, XCD-swizzled 1D grid ----------
// Best-measured MLP1 config (112 µs).  T1 bijective XCD swizzle, bm-fast
// flatten: each XCD owns a contiguous bn-slab -> its B slice (~1MB) stays
// L2-resident instead of both operands streaming cross-XCD.
template <int MODE>
__global__ __launch_bounds__(256, 4)
void gemm_bt(const u16* __restrict__ A, const u16* __restrict__ BT,
             const float* __restrict__ bias, const float* __restrict__ resid,
             void* __restrict__ outp, int mtiles, int ntiles, int N, int K) {
  __shared__ u16 sA[2][128 * 32];
  __shared__ u16 sB[2][128 * 32];
  const int t = threadIdx.x;
  const int w = t >> 6, l = t & 63;
  const int c = l & 15, g = l >> 4;
  const int wr = w >> 1, wc = w & 1;

  const int nwg = mtiles * ntiles;            // multiple of 8
  const int orig = blockIdx.x;
  const int wgid = (orig & 7) * (nwg >> 3) + (orig >> 3);
  const int bm = wgid % mtiles, bn = wgid / mtiles;   // bm-fast

  f32x4 acc[4][4] = {};

  const char* Ab = (const char*)(A + (size_t)bm * 128 * K);
  const char* Bb = (const char*)(BT + (size_t)bn * 128 * K);
  const size_t ldb = (size_t)K * 2;
  const int srow = t >> 2;
  const int scolb = (t & 3) * 16;
  const int ldsoff = w * 1024;

  auto stage = [&](int buf, int k0) {
#pragma unroll
    for (int i = 0; i < 2; ++i) {
      async16(Ab + (size_t)(srow + i * 64) * ldb + (size_t)k0 * 2 + scolb,
              (char*)sA[buf] + i * 4096 + ldsoff);
      async16(Bb + (size_t)(srow + i * 64) * ldb + (size_t)k0 * 2 + scolb,
              (char*)sB[buf] + i * 4096 + ldsoff);
    }
  };

  stage(0, 0);
  asm volatile("s_waitcnt vmcnt(0)" ::: "memory");
  __builtin_amdgcn_s_barrier();

  const int nt = K >> 5;
  for (int it = 0; it < nt; ++it) {
    const int cur = it & 1;
    if (it + 1 < nt) stage(cur ^ 1, (it + 1) << 5);
    bf16x8 af[4], bfr[4];
#pragma unroll
    for (int m = 0; m < 4; ++m)
      af[m] = *(const bf16x8*)&sA[cur][(wr * 64 + m * 16 + c) * 32 + g * 8];
#pragma unroll
    for (int n = 0; n < 4; ++n)
      bfr[n] = *(const bf16x8*)&sB[cur][(wc * 64 + n * 16 + c) * 32 + g * 8];
#pragma unroll
    for (int m = 0; m < 4; ++m)
#pragma unroll
      for (int n = 0; n < 4; ++n)
        acc[m][n] = __builtin_amdgcn_mfma_f32_16x16x32_bf16(af[m], bfr[n], acc[m][n], 0, 0, 0);
    asm volatile("s_waitcnt vmcnt(0)" ::: "memory");
    __builtin_amdgcn_s_barrier();
  }

  gemm_epilogue<MODE>(acc, bm, bn, wr, wc, c, g, bias, resid, outp, N);
}

// ---------- 2-phase GEMM, 128^2 tile, BK=64 (grid-limited GEMMs) ----------
template <int MODE>
__global__ __launch_bounds__(256, 2)
void gemm64(const u16* __restrict__ A, const u16* __restrict__ BT,
            const float* __restrict__ bias, const float* __restrict__ resid,
            void* __restrict__ outp, int M, int N, int K) {
  __shared__ u16 sA[2][128 * 64];
  __shared__ u16 sB[2][128 * 64];
  const int t = threadIdx.x;
  const int w = t >> 6, l = t & 63;
  const int c = l & 15, g = l >> 4;
  const int wr = w >> 1, wc = w & 1;
  const int bm = blockIdx.x, bn = blockIdx.y;

  f32x4 acc[4][4] = {};

  const char* Ab = (const char*)(A + (size_t)bm * 128 * K);
  const char* Bb = (const char*)(BT + (size_t)bn * 128 * K);
  const size_t ldb = (size_t)K * 2;

  int soff[4];
#pragma unroll
  for (int i = 0; i < 4; ++i) {
    const int o = i * 256 + t, row = o >> 3, ch = (o & 7) ^ (row & 7);
    soff[i] = row * (int)ldb + ch * 16;
  }

  auto stage = [&](int buf, int k0) {
    const int kb = k0 * 2;
#pragma unroll
    for (int i = 0; i < 4; ++i) {
      async16(Ab + (size_t)(soff[i] + kb), (char*)sA[buf] + (i * 256 + t) * 16);
      async16(Bb + (size_t)(soff[i] + kb), (char*)sB[buf] + (i * 256 + t) * 16);
    }
  };

  stage(0, 0);
  asm volatile("s_waitcnt vmcnt(0)" ::: "memory");
  __builtin_amdgcn_s_barrier();

  const int nt = K >> 6;
  for (int it = 0; it < nt; ++it) {
    const int cur = it & 1;
    if (it + 1 < nt) stage(cur ^ 1, (it + 1) << 6);
    bf16x8 af[4][2], bfr[4][2];
#pragma unroll
    for (int m = 0; m < 4; ++m) {
      const int row = wr * 64 + m * 16 + c;
#pragma unroll
      for (int ks = 0; ks < 2; ++ks)
        af[m][ks] = *(const bf16x8*)((const char*)sA[cur] + row * 128 + (((ks << 2) + g) ^ (row & 7)) * 16);
    }
#pragma unroll
    for (int n = 0; n < 4; ++n) {
      const int row = wc * 64 + n * 16 + c;
#pragma unroll
      for (int ks = 0; ks < 2; ++ks)
        bfr[n][ks] = *(const bf16x8*)((const char*)sB[cur] + row * 128 + (((ks << 2) + g) ^ (row & 7)) * 16);
    }
#pragma unroll
    for (int ks = 0; ks < 2; ++ks)
#pragma unroll
      for (int m = 0; m < 4; ++m)
#pragma unroll
        for (int n = 0; n < 4; ++n)
          acc[m][n] = __builtin_amdgcn_mfma_f32_16x16x32_bf16(af[m][ks], bfr[n][ks], acc[m][n], 0, 0, 0);
    asm volatile("s_waitcnt vmcnt(0)" ::: "memory");
    __builtin_amdgcn_s_barrier();
  }

  gemm_epilogue<MODE>(acc, bm, bn, wr, wc, c, g, bias, resid, outp, N);
}

// ---------- causal flash attention ----------
__global__ __launch_bounds__(256, 3)
void attn_kernel(const u16* __restrict__ q, const u16* __restrict__ k,
                 const u16* __restrict__ vT, u16* __restrict__ z) {
  __shared__ u16 sK[2][64 * 64];
  __shared__ u16 sV[2][64 * 64];
  __shared__ u16 pb[4][32 * 64];

  const int t = threadIdx.x, w = t >> 6, l = t & 63;
  const int c = l & 15, g = l >> 4;
  const int bh = blockIdx.y;
  const int qb0 = blockIdx.x * 128;
  const int qw0 = qb0 + w * 32;

  const u16* qbase = q  + (size_t)bh * SEQ * DHEAD;
  const u16* kbase = k  + (size_t)bh * SEQ * DHEAD;
  const u16* vbase = vT + (size_t)bh * DHEAD * SEQ;

  bf16x8 qf[2][2];
#pragma unroll
  for (int j = 0; j < 2; ++j)
#pragma unroll
    for (int hh = 0; hh < 2; ++hh)
      qf[j][hh] = *(const bf16x8*)&qbase[(size_t)(qw0 + j * 16 + c) * DHEAD + hh * 32 + g * 8];

  f32x4 o[4][2] = {};
  float m[2]  = {-3.0e38f, -3.0e38f};
  float ls[2] = {0.0f, 0.0f};

  const int r8 = l >> 3, ch = l & 7;
  const int sw16 = (ch ^ r8) * 16;

  auto stage = [&](int buf, int kt) {
    const int kb0 = kt * 64;
#pragma unroll
    for (int i = 0; i < 2; ++i) {
      const int row = w * 8 + i * 32 + r8;
      async16((const char*)kbase + (size_t)(kb0 + row) * 128 + sw16,
              (char*)sK[buf] + w * 1024 + i * 4096);
      async16((const char*)vbase + (size_t)row * (SEQ * 2) + (size_t)kb0 * 2 + sw16,
              (char*)sV[buf] + w * 1024 + i * 4096);
    }
  };

  const int nkt = blockIdx.x * 2 + 2;
  stage(0, 0);

  for (int kt = 0; kt < nkt; ++kt) {
    const int cur = kt & 1;
    if (kt + 1 < nkt) {
      stage(cur ^ 1, kt + 1);
      asm volatile("s_waitcnt vmcnt(4)" ::: "memory");
    } else {
      asm volatile("s_waitcnt vmcnt(0)" ::: "memory");
    }
    __builtin_amdgcn_s_barrier();

    const int kb0 = kt * 64;
    if (kb0 < qw0 + 32) {
      const u16* sKc = sK[cur];
      const u16* sVc = sV[cur];
      const int cx = c & 7;

      f32x4 st[4][2];
#pragma unroll
      for (int s = 0; s < 4; ++s) {
        const int row = s * 16 + c;
        bf16x8 kf0 = *(const bf16x8*)&sKc[row * 64 + ((0 + g) ^ cx) * 8];
        bf16x8 kf1 = *(const bf16x8*)&sKc[row * 64 + ((4 + g) ^ cx) * 8];
#pragma unroll
        for (int j = 0; j < 2; ++j) {
          f32x4 z4 = {};
          z4 = __builtin_amdgcn_mfma_f32_16x16x32_bf16(kf0, qf[j][0], z4, 0, 0, 0);
          z4 = __builtin_amdgcn_mfma_f32_16x16x32_bf16(kf1, qf[j][1], z4, 0, 0, 0);
          st[s][j] = z4;
        }
      }

      const bool full = (kb0 + 64 <= qw0 + 1);
      float tmax[2] = {-3.0e38f, -3.0e38f};
#pragma unroll
      for (int s = 0; s < 4; ++s)
#pragma unroll
        for (int j = 0; j < 2; ++j)
#pragma unroll
          for (int i = 0; i < 4; ++i) {
            float vsc = st[s][j][i] * 0.125f;
            if (!full) {
              const int key = kb0 + s * 16 + g * 4 + i;
              vsc = (key <= qw0 + j * 16 + c) ? vsc : -1.0e30f;
            }
            st[s][j][i] = vsc;
            tmax[j] = fmaxf(tmax[j], vsc);
          }
#pragma unroll
      for (int j = 0; j < 2; ++j) {
        tmax[j] = fmaxf(tmax[j], __shfl_xor(tmax[j], 16));
        tmax[j] = fmaxf(tmax[j], __shfl_xor(tmax[j], 32));
      }
      float mnew[2], sc[2], psum[2];
#pragma unroll
      for (int j = 0; j < 2; ++j) {
        mnew[j] = fmaxf(m[j], tmax[j]);
        sc[j]   = __expf(m[j] - mnew[j]);
        psum[j] = 0.0f;
      }
#pragma unroll
      for (int s = 0; s < 4; ++s)
#pragma unroll
        for (int j = 0; j < 2; ++j)
#pragma unroll
          for (int i = 0; i < 4; ++i) {
            const float pv = __expf(st[s][j][i] - mnew[j]);
            st[s][j][i] = pv;
            psum[j] += pv;
          }
#pragma unroll
      for (int j = 0; j < 2; ++j) {
        psum[j] += __shfl_xor(psum[j], 16);
        psum[j] += __shfl_xor(psum[j], 32);
        ls[j] = ls[j] * sc[j] + psum[j];
        m[j]  = mnew[j];
#pragma unroll
        for (int d = 0; d < 4; ++d) o[d][j] = o[d][j] * sc[j];
      }

      u16* pw = pb[w];
#pragma unroll
      for (int s = 0; s < 4; ++s)
#pragma unroll
        for (int j = 0; j < 2; ++j) {
          const int row = j * 16 + c;
          const int swz = (s * 2 + (g >> 1)) ^ cx;
          ushort4 pv4;
          pv4.x = f2bf(st[s][j][0]); pv4.y = f2bf(st[s][j][1]);
          pv4.z = f2bf(st[s][j][2]); pv4.w = f2bf(st[s][j][3]);
          *(ushort4*)&pw[row * 64 + swz * 8 + (g & 1) * 4] = pv4;
        }

      bf16x8 pf[2][2];
#pragma unroll
      for (int j = 0; j < 2; ++j)
#pragma unroll
        for (int ks = 0; ks < 2; ++ks)
          pf[j][ks] = *(const bf16x8*)&pw[(j * 16 + c) * 64 + ((ks * 4 + g) ^ cx) * 8];

#pragma unroll
      for (int d = 0; d < 4; ++d) {
        const int vrow = d * 16 + c;
#pragma unroll
        for (int ks = 0; ks < 2; ++ks) {
          bf16x8 vf = *(const bf16x8*)&sVc[vrow * 64 + ((ks * 4 + g) ^ cx) * 8];
#pragma unroll
          for (int j = 0; j < 2; ++j)
            o[d][j] = __builtin_amdgcn_mfma_f32_16x16x32_bf16(vf, pf[j][ks], o[d][j], 0, 0, 0);
        }
      }
    }
    __builtin_amdgcn_s_barrier();
  }

  const int b = bh >> 4, h = bh & 15;
#pragma unroll
  for (int j = 0; j < 2; ++j) {
    const float inv = 1.0f / ls[j];
    const int qrow = qw0 + j * 16 + c;
    u16* zr = z + ((size_t)b * SEQ + qrow) * D_MODEL + h * DHEAD;
#pragma unroll
    for (int d = 0; d < 4; ++d) {
      ushort4 ov;
      ov.x = f2bf(o[d][j][0] * inv); ov.y = f2bf(o[d][j][1] * inv);
      ov.z = f2bf(o[d][j][2] * inv); ov.w = f2bf(o[d][j][3] * inv);
      *(ushort4*)&zr[d * 16 + g * 4] = ov;
    }
  }
}

// ---------- host ----------
extern "C" void kernel_launch(void* const* d_in, const int* in_sizes, int n_in,
                              void* d_out, int out_size, void* d_ws, size_t ws_size,
                              hipStream_t stream) {
  (void)in_sizes; (void)n_in; (void)out_size; (void)ws_size;
  const float* x   = (const float*)d_in[0];
  const float* g1  = (const float*)d_in[1];
  const float* s1  = (const float*)d_in[2];
  const float* Wq  = (const float*)d_in[3];
  const float* Wk  = (const float*)d_in[4];
  const float* Wv  = (const float*)d_in[5];
  const float* Wo  = (const float*)d_in[6];
  const float* bo  = (const float*)d_in[7];
  const float* g2  = (const float*)d_in[8];
  const float* s2  = (const float*)d_in[9];
  const float* W1  = (const float*)d_in[10];
  const float* b1  = (const float*)d_in[11];
  const float* W2  = (const float*)d_in[12];
  const float* b2  = (const float*)d_in[13];
  float* out = (float*)d_out;
  char* ws = (char*)d_ws;
  const size_t MB = 1024 * 1024;

  u16* wqT = (u16*)(ws + 0 * MB);     // 2 MB (wq/wk/wv/wo contiguous)
  u16* wkT = (u16*)(ws + 2 * MB);
  u16* wvT = (u16*)(ws + 4 * MB);
  u16* woT = (u16*)(ws + 6 * MB);
  u16* w1T = (u16*)(ws + 8 * MB);     // 8 MB  [4096,1024]
  u16* w2T = (u16*)(ws + 16 * MB);    // 8 MB  [1024,4096]
  u16* x1  = (u16*)(ws + 24 * MB);    // 16 MB
  u16* qb  = (u16*)(ws + 40 * MB);    // 16 MB
  u16* kb  = (u16*)(ws + 56 * MB);    // 16 MB
  u16* vb  = (u16*)(ws + 72 * MB);    // 16 MB
  u16* hb  = (u16*)(ws + 24 * MB);    // 64 MB, aliases x1/q/k/v (dead by MLP1)
  u16* zb  = (u16*)(ws + 88 * MB);    // 16 MB
  u16* y1  = (u16*)(ws + 88 * MB);    // 16 MB, aliases zb (dead after Wo proj)
  u16* yb  = (u16*)(ws + 104 * MB);   // 16 MB  bf16 y  -> total 120 MB

  // 1. weight convert + transpose
  wconv4_kernel<<<dim3(32, 32, 4), 256, 0, stream>>>(Wq, Wk, Wv, Wo, wqT);
  wconv_kernel<<<dim3(128, 32), 256, 0, stream>>>(W1, w1T, 1024, 4096);
  wconv_kernel<<<dim3(32, 128), 256, 0, stream>>>(W2, w2T, 4096, 1024);
  // 2. LN1
  ln_kernel<<<NROW, 256, 0, stream>>>(x, g1, s1, x1);
  // 3. QKV projections — BK=64
  gemm64<MODE_QK><<<dim3(64, 8), 256, 0, stream>>>(x1, wqT, nullptr, nullptr, qb, NROW, 1024, 1024);
  gemm64<MODE_QK><<<dim3(64, 8), 256, 0, stream>>>(x1, wkT, nullptr, nullptr, kb, NROW, 1024, 1024);
  gemm64<MODE_VT><<<dim3(64, 8), 256, 0, stream>>>(x1, wvT, nullptr, nullptr, vb, NROW, 1024, 1024);
  // 4. attention
  attn_kernel<<<dim3(8, 128), 256, 0, stream>>>(qb, kb, vb, zb);
  // 5. output projection + residual -> bf16 y (BK=64)
  gemm64<MODE_YRES><<<dim3(64, 8), 256, 0, stream>>>(zb, woT, bo, x, yb, NROW, 1024, 1024);
  // 6. LN2 (bf16 input)
  ln_bf16_kernel<<<NROW, 256, 0, stream>>>(yb, g2, s2, y1);
  // 7. MLP up + GELU — best-measured config (BK=32, 4 blk/CU) + XCD swizzle
  gemm_bt<MODE_GELU><<<2048, 256, 0, stream>>>(y1, w1T, b1, nullptr,
                                               hb, 64, 32, 4096, 1024);
  // 8. MLP down + bias + bf16-y residual -> fp32 out (BK=64)
  gemm64<MODE_OUT><<<dim3(64, 8), 256, 0, stream>>>(hb, w2T, b2, (const float*)yb,
                                                    out, NROW, 1024, 4096);
}

// Round 15
// 358.202 us; speedup vs baseline: 1.0260x; 1.0260x over previous
//
#include <hip/hip_runtime.h>

typedef unsigned short u16;
typedef __bf16 bf16x8 __attribute__((ext_vector_type(8)));
typedef float f32x4 __attribute__((ext_vector_type(4)));

#define D_MODEL 1024
#define NHEAD 16
#define DHEAD 64
#define BATCH 8
#define SEQ 1024
#define NROW 8192   // BATCH*SEQ

// ---------- helpers ----------
__device__ __forceinline__ u16 f2bf(float f) {
  union { float f; unsigned int u; } a; a.f = f;
  unsigned int u = a.u;
  return (u16)((u + 0x7fffu + ((u >> 16) & 1u)) >> 16);
}

__device__ __forceinline__ float bf2f(u16 b) {
  union { unsigned int u; float f; } a; a.u = ((unsigned int)b) << 16;
  return a.f;
}

// gelu_tanh(x) == x * sigmoid(2*c*(x+0.044715x^3)); single v_exp_f32, NaN-safe.
__device__ __forceinline__ float gelu_f(float x) {
  float y = 0.79788456080286535588f * (x + 0.044715f * x * x * x);
  return x / (1.0f + __expf(-2.0f * y));
}

__device__ __forceinline__ void async16(const void* gsrc, void* ldst) {
  __builtin_amdgcn_global_load_lds((__attribute__((address_space(1))) void*)gsrc,
                                   (__attribute__((address_space(3))) void*)ldst,
                                   16, 0, 0);
}

// ---------- 4x weight fp32 [1024,1024] -> bf16 W^T, z-indexed ----------
__global__ __launch_bounds__(256)
void wconv4_kernel(const float* __restrict__ Wa, const float* __restrict__ Wb,
                   const float* __restrict__ Wc, const float* __restrict__ Wd,
                   u16* __restrict__ WT) {
  const float* Ws[4] = {Wa, Wb, Wc, Wd};
  const float* W = Ws[blockIdx.z];
  u16* dst = WT + (size_t)blockIdx.z * 1024 * 1024;
  __shared__ float tile[32][33];
  const int tx = threadIdx.x & 31, ty = threadIdx.x >> 5;
  const int n0 = blockIdx.x * 32, k0 = blockIdx.y * 32;
#pragma unroll
  for (int r = 0; r < 4; ++r)
    tile[ty + r * 8][tx] = W[(size_t)(k0 + ty + r * 8) * 1024 + n0 + tx];
  __syncthreads();
#pragma unroll
  for (int r = 0; r < 4; ++r)
    dst[(size_t)(n0 + ty + r * 8) * 1024 + k0 + tx] = f2bf(tile[tx][ty + r * 8]);
}

// ---------- weight fp32 [K,N] -> bf16 W^T [N,K] ----------
__global__ __launch_bounds__(256)
void wconv_kernel(const float* __restrict__ W, u16* __restrict__ WT, int K, int N) {
  __shared__ float tile[32][33];
  const int tx = threadIdx.x & 31, ty = threadIdx.x >> 5;
  const int n0 = blockIdx.x * 32, k0 = blockIdx.y * 32;
#pragma unroll
  for (int r = 0; r < 4; ++r)
    tile[ty + r * 8][tx] = W[(size_t)(k0 + ty + r * 8) * N + n0 + tx];
  __syncthreads();
#pragma unroll
  for (int r = 0; r < 4; ++r)
    WT[(size_t)(n0 + ty + r * 8) * K + k0 + tx] = f2bf(tile[tx][ty + r * 8]);
}

// ---------- layernorm fp32 -> bf16 ----------
__global__ __launch_bounds__(256)
void ln_kernel(const float* __restrict__ x, const float* __restrict__ gamma,
               const float* __restrict__ beta, u16* __restrict__ out) {
  const int row = blockIdx.x, t = threadIdx.x;
  const float4 v = ((const float4*)(x + (size_t)row * D_MODEL))[t];
  float s  = v.x + v.y + v.z + v.w;
  float s2 = v.x * v.x + v.y * v.y + v.z * v.z + v.w * v.w;
#pragma unroll
  for (int off = 32; off >= 1; off >>= 1) {
    s  += __shfl_down(s, off);
    s2 += __shfl_down(s2, off);
  }
  __shared__ float red[8];
  const int w = t >> 6, l = t & 63;
  if (l == 0) { red[w] = s; red[4 + w] = s2; }
  __syncthreads();
  s  = red[0] + red[1] + red[2] + red[3];
  s2 = red[4] + red[5] + red[6] + red[7];
  const float mean = s * (1.0f / D_MODEL);
  const float var  = s2 * (1.0f / D_MODEL) - mean * mean;
  const float inv  = rsqrtf(var + 1e-5f);
  const float4 ga = ((const float4*)gamma)[t];
  const float4 be = ((const float4*)beta)[t];
  ushort4 ov;
  ov.x = f2bf((v.x - mean) * inv * ga.x + be.x);
  ov.y = f2bf((v.y - mean) * inv * ga.y + be.y);
  ov.z = f2bf((v.z - mean) * inv * ga.z + be.z);
  ov.w = f2bf((v.w - mean) * inv * ga.w + be.w);
  ((ushort4*)out)[(size_t)row * 256 + t] = ov;
}

// ---------- layernorm bf16 -> bf16 ----------
__global__ __launch_bounds__(256)
void ln_bf16_kernel(const u16* __restrict__ x, const float* __restrict__ gamma,
                    const float* __restrict__ beta, u16* __restrict__ out) {
  const int row = blockIdx.x, t = threadIdx.x;
  const ushort4 bv = ((const ushort4*)(x + (size_t)row * D_MODEL))[t];
  float4 v;
  v.x = bf2f(bv.x); v.y = bf2f(bv.y); v.z = bf2f(bv.z); v.w = bf2f(bv.w);
  float s  = v.x + v.y + v.z + v.w;
  float s2 = v.x * v.x + v.y * v.y + v.z * v.z + v.w * v.w;
#pragma unroll
  for (int off = 32; off >= 1; off >>= 1) {
    s  += __shfl_down(s, off);
    s2 += __shfl_down(s2, off);
  }
  __shared__ float red[8];
  const int w = t >> 6, l = t & 63;
  if (l == 0) { red[w] = s; red[4 + w] = s2; }
  __syncthreads();
  s  = red[0] + red[1] + red[2] + red[3];
  s2 = red[4] + red[5] + red[6] + red[7];
  const float mean = s * (1.0f / D_MODEL);
  const float var  = s2 * (1.0f / D_MODEL) - mean * mean;
  const float inv  = rsqrtf(var + 1e-5f);
  const float4 ga = ((const float4*)gamma)[t];
  const float4 be = ((const float4*)beta)[t];
  ushort4 ov;
  ov.x = f2bf((v.x - mean) * inv * ga.x + be.x);
  ov.y = f2bf((v.y - mean) * inv * ga.y + be.y);
  ov.z = f2bf((v.z - mean) * inv * ga.z + be.z);
  ov.w = f2bf((v.w - mean) * inv * ga.w + be.w);
  ((ushort4*)out)[(size_t)row * 256 + t] = ov;
}

#define MODE_QK 0
#define MODE_VT 1
#define MODE_YRES 2   // bf16 y = v + bias + f32 resid
#define MODE_GELU 3
#define MODE_OUT 4    // f32 out = v + bias + bf16 resid

// ---------- epilogue for 128^2-tile GEMM ----------
template <int MODE>
__device__ __forceinline__ void gemm_epilogue(f32x4 (&acc)[4][4], int bm, int bn,
                                              int wr, int wc, int c, int g,
                                              const float* bias, const float* resid,
                                              void* outp, int N) {
#pragma unroll
  for (int m = 0; m < 4; ++m) {
    const int r0 = bm * 128 + wr * 64 + m * 16 + g * 4;
#pragma unroll
    for (int n = 0; n < 4; ++n) {
      const int cc = bn * 128 + wc * 64 + n * 16 + c;
#pragma unroll
      for (int i = 0; i < 4; ++i) {
        const int r = r0 + i;
        const float v = acc[m][n][i];
        if constexpr (MODE == MODE_QK) {
          ((u16*)outp)[(((size_t)(r >> 10) * NHEAD + (cc >> 6)) * SEQ + (r & 1023)) * DHEAD + (cc & 63)] = f2bf(v);
        } else if constexpr (MODE == MODE_VT) {
          ((u16*)outp)[(((size_t)(r >> 10) * NHEAD + (cc >> 6)) * DHEAD + (cc & 63)) * SEQ + (r & 1023)] = f2bf(v);
        } else if constexpr (MODE == MODE_YRES) {
          const size_t idx = (size_t)r * N + cc;
          ((u16*)outp)[idx] = f2bf(v + bias[cc] + resid[idx]);
        } else if constexpr (MODE == MODE_OUT) {
          const size_t idx = (size_t)r * N + cc;
          ((float*)outp)[idx] = v + bias[cc] + bf2f(((const u16*)resid)[idx]);
        } else {
          const size_t idx = (size_t)r * N + cc;
          ((u16*)outp)[idx] = f2bf(gelu_f(v + bias[cc]));
        }
      }
    }
  }
}

// ---------- 2-phase GEMM, 128^2 tile, BK=64 (grid-limited GEMMs) ----------
template <int MODE>
__global__ __launch_bounds__(256, 2)
void gemm64(const u16* __restrict__ A, const u16* __restrict__ BT,
            const float* __restrict__ bias, const float* __restrict__ resid,
            void* __restrict__ outp, int M, int N, int K) {
  __shared__ u16 sA[2][128 * 64];
  __shared__ u16 sB[2][128 * 64];
  const int t = threadIdx.x;
  const int w = t >> 6, l = t & 63;
  const int c = l & 15, g = l >> 4;
  const int wr = w >> 1, wc = w & 1;
  const int bm = blockIdx.x, bn = blockIdx.y;

  f32x4 acc[4][4] = {};

  const char* Ab = (const char*)(A + (size_t)bm * 128 * K);
  const char* Bb = (const char*)(BT + (size_t)bn * 128 * K);
  const size_t ldb = (size_t)K * 2;

  int soff[4];
#pragma unroll
  for (int i = 0; i < 4; ++i) {
    const int o = i * 256 + t, row = o >> 3, ch = (o & 7) ^ (row & 7);
    soff[i] = row * (int)ldb + ch * 16;
  }

  auto stage = [&](int buf, int k0) {
    const int kb = k0 * 2;
#pragma unroll
    for (int i = 0; i < 4; ++i) {
      async16(Ab + (size_t)(soff[i] + kb), (char*)sA[buf] + (i * 256 + t) * 16);
      async16(Bb + (size_t)(soff[i] + kb), (char*)sB[buf] + (i * 256 + t) * 16);
    }
  };

  stage(0, 0);
  asm volatile("s_waitcnt vmcnt(0)" ::: "memory");
  __builtin_amdgcn_s_barrier();

  const int nt = K >> 6;
  for (int it = 0; it < nt; ++it) {
    const int cur = it & 1;
    if (it + 1 < nt) stage(cur ^ 1, (it + 1) << 6);
    bf16x8 af[4][2], bfr[4][2];
#pragma unroll
    for (int m = 0; m < 4; ++m) {
      const int row = wr * 64 + m * 16 + c;
#pragma unroll
      for (int ks = 0; ks < 2; ++ks)
        af[m][ks] = *(const bf16x8*)((const char*)sA[cur] + row * 128 + (((ks << 2) + g) ^ (row & 7)) * 16);
    }
#pragma unroll
    for (int n = 0; n < 4; ++n) {
      const int row = wc * 64 + n * 16 + c;
#pragma unroll
      for (int ks = 0; ks < 2; ++ks)
        bfr[n][ks] = *(const bf16x8*)((const char*)sB[cur] + row * 128 + (((ks << 2) + g) ^ (row & 7)) * 16);
    }
#pragma unroll
    for (int ks = 0; ks < 2; ++ks)
#pragma unroll
      for (int m = 0; m < 4; ++m)
#pragma unroll
        for (int n = 0; n < 4; ++n)
          acc[m][n] = __builtin_amdgcn_mfma_f32_16x16x32_bf16(af[m][ks], bfr[n][ks], acc[m][n], 0, 0, 0);
    asm volatile("s_waitcnt vmcnt(0)" ::: "memory");
    __builtin_amdgcn_s_barrier();
  }

  gemm_epilogue<MODE>(acc, bm, bn, wr, wc, c, g, bias, resid, outp, N);
}

// ---------- batched QKV: z in {0:Q, 1:K, 2:V}, weight = wqkvT + z*1M elems ----------
// z-major dispatch == 3 sequential GEMMs in one launch (saves 2 launch gaps).
__global__ __launch_bounds__(256, 2)
void gemm64_qkv3(const u16* __restrict__ A, const u16* __restrict__ wqkvT,
                 u16* __restrict__ qb, u16* __restrict__ kb, u16* __restrict__ vb,
                 int K) {
  __shared__ u16 sA[2][128 * 64];
  __shared__ u16 sB[2][128 * 64];
  const int t = threadIdx.x;
  const int w = t >> 6, l = t & 63;
  const int c = l & 15, g = l >> 4;
  const int wr = w >> 1, wc = w & 1;
  const int bm = blockIdx.x, bn = blockIdx.y, z = blockIdx.z;

  f32x4 acc[4][4] = {};

  const char* Ab = (const char*)(A + (size_t)bm * 128 * K);
  const char* Bb = (const char*)(wqkvT + ((size_t)z << 20) + (size_t)bn * 128 * K);
  const size_t ldb = (size_t)K * 2;

  int soff[4];
#pragma unroll
  for (int i = 0; i < 4; ++i) {
    const int o = i * 256 + t, row = o >> 3, ch = (o & 7) ^ (row & 7);
    soff[i] = row * (int)ldb + ch * 16;
  }

  auto stage = [&](int buf, int k0) {
    const int kb2 = k0 * 2;
#pragma unroll
    for (int i = 0; i < 4; ++i) {
      async16(Ab + (size_t)(soff[i] + kb2), (char*)sA[buf] + (i * 256 + t) * 16);
      async16(Bb + (size_t)(soff[i] + kb2), (char*)sB[buf] + (i * 256 + t) * 16);
    }
  };

  stage(0, 0);
  asm volatile("s_waitcnt vmcnt(0)" ::: "memory");
  __builtin_amdgcn_s_barrier();

  const int nt = K >> 6;
  for (int it = 0; it < nt; ++it) {
    const int cur = it & 1;
    if (it + 1 < nt) stage(cur ^ 1, (it + 1) << 6);
    bf16x8 af[4][2], bfr[4][2];
#pragma unroll
    for (int m = 0; m < 4; ++m) {
      const int row = wr * 64 + m * 16 + c;
#pragma unroll
      for (int ks = 0; ks < 2; ++ks)
        af[m][ks] = *(const bf16x8*)((const char*)sA[cur] + row * 128 + (((ks << 2) + g) ^ (row & 7)) * 16);
    }
#pragma unroll
    for (int n = 0; n < 4; ++n) {
      const int row = wc * 64 + n * 16 + c;
#pragma unroll
      for (int ks = 0; ks < 2; ++ks)
        bfr[n][ks] = *(const bf16x8*)((const char*)sB[cur] + row * 128 + (((ks << 2) + g) ^ (row & 7)) * 16);
    }
#pragma unroll
    for (int ks = 0; ks < 2; ++ks)
#pragma unroll
      for (int m = 0; m < 4; ++m)
#pragma unroll
        for (int n = 0; n < 4; ++n)
          acc[m][n] = __builtin_amdgcn_mfma_f32_16x16x32_bf16(af[m][ks], bfr[n][ks], acc[m][n], 0, 0, 0);
    asm volatile("s_waitcnt vmcnt(0)" ::: "memory");
    __builtin_amdgcn_s_barrier();
  }

  // epilogue: head-split scatter; z<2 -> [b,h,t,dh], z==2 -> [b,h,dh,t]
  u16* outp = (z == 0) ? qb : (z == 1) ? kb : vb;
#pragma unroll
  for (int m = 0; m < 4; ++m) {
    const int r0 = bm * 128 + wr * 64 + m * 16 + g * 4;
#pragma unroll
    for (int n = 0; n < 4; ++n) {
      const int cc = bn * 128 + wc * 64 + n * 16 + c;
#pragma unroll
      for (int i = 0; i < 4; ++i) {
        const int r = r0 + i;
        const float v = acc[m][n][i];
        if (z < 2)
          outp[(((size_t)(r >> 10) * NHEAD + (cc >> 6)) * SEQ + (r & 1023)) * DHEAD + (cc & 63)] = f2bf(v);
        else
          outp[(((size_t)(r >> 10) * NHEAD + (cc >> 6)) * DHEAD + (cc & 63)) * SEQ + (r & 1023)] = f2bf(v);
      }
    }
  }
}

// ---------- 2-phase GEMM, 256^2 tile, BK=64, 8 waves (MLP1; best-measured) ----------
template <int MODE>
__global__ __launch_bounds__(512, 2)
void gemm256(const u16* __restrict__ A, const u16* __restrict__ BT,
             const float* __restrict__ bias, const float* __restrict__ resid,
             void* __restrict__ outp, int M, int N, int K) {
  __shared__ u16 sA[2][256 * 64];   // 32 KB each
  __shared__ u16 sB[2][256 * 64];
  const int t = threadIdx.x;
  const int w = t >> 6, l = t & 63;
  const int c = l & 15, g = l >> 4;
  const int wr = w >> 2, wc = w & 3;
  const int bm = blockIdx.x, bn = blockIdx.y;

  f32x4 acc[8][4] = {};

  const char* Ab = (const char*)(A + (size_t)bm * 256 * K);
  const char* Bb = (const char*)(BT + (size_t)bn * 256 * K);
  const size_t ldb = (size_t)K * 2;

  int soff[4];
#pragma unroll
  for (int i = 0; i < 4; ++i) {
    const int o = i * 512 + t, row = o >> 3, ch = (o & 7) ^ (row & 7);
    soff[i] = row * (int)ldb + ch * 16;
  }

  auto stage = [&](int buf, int k0) {
    const int kb = k0 * 2;
#pragma unroll
    for (int i = 0; i < 4; ++i) {
      async16(Ab + (size_t)(soff[i] + kb), (char*)sA[buf] + (i * 512 + t) * 16);
      async16(Bb + (size_t)(soff[i] + kb), (char*)sB[buf] + (i * 512 + t) * 16);
    }
  };

  stage(0, 0);
  asm volatile("s_waitcnt vmcnt(0)" ::: "memory");
  __builtin_amdgcn_s_barrier();

  const int nt = K >> 6;
  for (int it = 0; it < nt; ++it) {
    const int cur = it & 1;
    if (it + 1 < nt) stage(cur ^ 1, (it + 1) << 6);
    bf16x8 bfr[4][2];
#pragma unroll
    for (int n = 0; n < 4; ++n) {
      const int row = wc * 64 + n * 16 + c;
#pragma unroll
      for (int ks = 0; ks < 2; ++ks)
        bfr[n][ks] = *(const bf16x8*)((const char*)sB[cur] + row * 128 + (((ks << 2) + g) ^ (row & 7)) * 16);
    }
#pragma unroll
    for (int m2 = 0; m2 < 4; ++m2) {
      bf16x8 af2[2][2];
#pragma unroll
      for (int mi = 0; mi < 2; ++mi) {
        const int row = wr * 128 + (m2 * 2 + mi) * 16 + c;
#pragma unroll
        for (int ks = 0; ks < 2; ++ks)
          af2[mi][ks] = *(const bf16x8*)((const char*)sA[cur] + row * 128 + (((ks << 2) + g) ^ (row & 7)) * 16);
      }
#pragma unroll
      for (int ks = 0; ks < 2; ++ks)
#pragma unroll
        for (int mi = 0; mi < 2; ++mi)
#pragma unroll
          for (int n = 0; n < 4; ++n)
            acc[m2 * 2 + mi][n] = __builtin_amdgcn_mfma_f32_16x16x32_bf16(
                af2[mi][ks], bfr[n][ks], acc[m2 * 2 + mi][n], 0, 0, 0);
    }
    asm volatile("s_waitcnt vmcnt(0)" ::: "memory");
    __builtin_amdgcn_s_barrier();
  }

#pragma unroll
  for (int m = 0; m < 8; ++m) {
    const int r0 = bm * 256 + wr * 128 + m * 16 + g * 4;
#pragma unroll
    for (int n = 0; n < 4; ++n) {
      const int cc = bn * 256 + wc * 64 + n * 16 + c;
#pragma unroll
      for (int i = 0; i < 4; ++i) {
        const int r = r0 + i;
        const float v = acc[m][n][i];
        if constexpr (MODE == MODE_YRES) {
          const size_t idx = (size_t)r * N + cc;
          ((u16*)outp)[idx] = f2bf(v + bias[cc] + resid[idx]);
        } else if constexpr (MODE == MODE_OUT) {
          const size_t idx = (size_t)r * N + cc;
          ((float*)outp)[idx] = v + bias[cc] + bf2f(((const u16*)resid)[idx]);
        } else {
          const size_t idx = (size_t)r * N + cc;
          ((u16*)outp)[idx] = f2bf(gelu_f(v + bias[cc]));
        }
      }
    }
  }
}

// ---------- causal flash attention ----------
__global__ __launch_bounds__(256, 3)
void attn_kernel(const u16* __restrict__ q, const u16* __restrict__ k,
                 const u16* __restrict__ vT, u16* __restrict__ z) {
  __shared__ u16 sK[2][64 * 64];
  __shared__ u16 sV[2][64 * 64];
  __shared__ u16 pb[4][32 * 64];

  const int t = threadIdx.x, w = t >> 6, l = t & 63;
  const int c = l & 15, g = l >> 4;
  const int bh = blockIdx.y;
  const int qb0 = blockIdx.x * 128;
  const int qw0 = qb0 + w * 32;

  const u16* qbase = q  + (size_t)bh * SEQ * DHEAD;
  const u16* kbase = k  + (size_t)bh * SEQ * DHEAD;
  const u16* vbase = vT + (size_t)bh * DHEAD * SEQ;

  bf16x8 qf[2][2];
#pragma unroll
  for (int j = 0; j < 2; ++j)
#pragma unroll
    for (int hh = 0; hh < 2; ++hh)
      qf[j][hh] = *(const bf16x8*)&qbase[(size_t)(qw0 + j * 16 + c) * DHEAD + hh * 32 + g * 8];

  f32x4 o[4][2] = {};
  float m[2]  = {-3.0e38f, -3.0e38f};
  float ls[2] = {0.0f, 0.0f};

  const int r8 = l >> 3, ch = l & 7;
  const int sw16 = (ch ^ r8) * 16;

  auto stage = [&](int buf, int kt) {
    const int kb0 = kt * 64;
#pragma unroll
    for (int i = 0; i < 2; ++i) {
      const int row = w * 8 + i * 32 + r8;
      async16((const char*)kbase + (size_t)(kb0 + row) * 128 + sw16,
              (char*)sK[buf] + w * 1024 + i * 4096);
      async16((const char*)vbase + (size_t)row * (SEQ * 2) + (size_t)kb0 * 2 + sw16,
              (char*)sV[buf] + w * 1024 + i * 4096);
    }
  };

  const int nkt = blockIdx.x * 2 + 2;
  stage(0, 0);

  for (int kt = 0; kt < nkt; ++kt) {
    const int cur = kt & 1;
    if (kt + 1 < nkt) {
      stage(cur ^ 1, kt + 1);
      asm volatile("s_waitcnt vmcnt(4)" ::: "memory");
    } else {
      asm volatile("s_waitcnt vmcnt(0)" ::: "memory");
    }
    __builtin_amdgcn_s_barrier();

    const int kb0 = kt * 64;
    if (kb0 < qw0 + 32) {
      const u16* sKc = sK[cur];
      const u16* sVc = sV[cur];
      const int cx = c & 7;

      f32x4 st[4][2];
#pragma unroll
      for (int s = 0; s < 4; ++s) {
        const int row = s * 16 + c;
        bf16x8 kf0 = *(const bf16x8*)&sKc[row * 64 + ((0 + g) ^ cx) * 8];
        bf16x8 kf1 = *(const bf16x8*)&sKc[row * 64 + ((4 + g) ^ cx) * 8];
#pragma unroll
        for (int j = 0; j < 2; ++j) {
          f32x4 z4 = {};
          z4 = __builtin_amdgcn_mfma_f32_16x16x32_bf16(kf0, qf[j][0], z4, 0, 0, 0);
          z4 = __builtin_amdgcn_mfma_f32_16x16x32_bf16(kf1, qf[j][1], z4, 0, 0, 0);
          st[s][j] = z4;
        }
      }

      const bool full = (kb0 + 64 <= qw0 + 1);
      float tmax[2] = {-3.0e38f, -3.0e38f};
#pragma unroll
      for (int s = 0; s < 4; ++s)
#pragma unroll
        for (int j = 0; j < 2; ++j)
#pragma unroll
          for (int i = 0; i < 4; ++i) {
            float vsc = st[s][j][i] * 0.125f;
            if (!full) {
              const int key = kb0 + s * 16 + g * 4 + i;
              vsc = (key <= qw0 + j * 16 + c) ? vsc : -1.0e30f;
            }
            st[s][j][i] = vsc;
            tmax[j] = fmaxf(tmax[j], vsc);
          }
#pragma unroll
      for (int j = 0; j < 2; ++j) {
        tmax[j] = fmaxf(tmax[j], __shfl_xor(tmax[j], 16));
        tmax[j] = fmaxf(tmax[j], __shfl_xor(tmax[j], 32));
      }
      float mnew[2], sc[2], psum[2];
#pragma unroll
      for (int j = 0; j < 2; ++j) {
        mnew[j] = fmaxf(m[j], tmax[j]);
        sc[j]   = __expf(m[j] - mnew[j]);
        psum[j] = 0.0f;
      }
#pragma unroll
      for (int s = 0; s < 4; ++s)
#pragma unroll
        for (int j = 0; j < 2; ++j)
#pragma unroll
          for (int i = 0; i < 4; ++i) {
            const float pv = __expf(st[s][j][i] - mnew[j]);
            st[s][j][i] = pv;
            psum[j] += pv;
          }
#pragma unroll
      for (int j = 0; j < 2; ++j) {
        psum[j] += __shfl_xor(psum[j], 16);
        psum[j] += __shfl_xor(psum[j], 32);
        ls[j] = ls[j] * sc[j] + psum[j];
        m[j]  = mnew[j];
#pragma unroll
        for (int d = 0; d < 4; ++d) o[d][j] = o[d][j] * sc[j];
      }

      u16* pw = pb[w];
#pragma unroll
      for (int s = 0; s < 4; ++s)
#pragma unroll
        for (int j = 0; j < 2; ++j) {
          const int row = j * 16 + c;
          const int swz = (s * 2 + (g >> 1)) ^ cx;
          ushort4 pv4;
          pv4.x = f2bf(st[s][j][0]); pv4.y = f2bf(st[s][j][1]);
          pv4.z = f2bf(st[s][j][2]); pv4.w = f2bf(st[s][j][3]);
          *(ushort4*)&pw[row * 64 + swz * 8 + (g & 1) * 4] = pv4;
        }

      bf16x8 pf[2][2];
#pragma unroll
      for (int j = 0; j < 2; ++j)
#pragma unroll
        for (int ks = 0; ks < 2; ++ks)
          pf[j][ks] = *(const bf16x8*)&pw[(j * 16 + c) * 64 + ((ks * 4 + g) ^ cx) * 8];

#pragma unroll
      for (int d = 0; d < 4; ++d) {
        const int vrow = d * 16 + c;
#pragma unroll
        for (int ks = 0; ks < 2; ++ks) {
          bf16x8 vf = *(const bf16x8*)&sVc[vrow * 64 + ((ks * 4 + g) ^ cx) * 8];
#pragma unroll
          for (int j = 0; j < 2; ++j)
            o[d][j] = __builtin_amdgcn_mfma_f32_16x16x32_bf16(vf, pf[j][ks], o[d][j], 0, 0, 0);
        }
      }
    }
    __builtin_amdgcn_s_barrier();
  }

  const int b = bh >> 4, h = bh & 15;
#pragma unroll
  for (int j = 0; j < 2; ++j) {
    const float inv = 1.0f / ls[j];
    const int qrow = qw0 + j * 16 + c;
    u16* zr = z + ((size_t)b * SEQ + qrow) * D_MODEL + h * DHEAD;
#pragma unroll
    for (int d = 0; d < 4; ++d) {
      ushort4 ov;
      ov.x = f2bf(o[d][j][0] * inv); ov.y = f2bf(o[d][j][1] * inv);
      ov.z = f2bf(o[d][j][2] * inv); ov.w = f2bf(o[d][j][3] * inv);
      *(ushort4*)&zr[d * 16 + g * 4] = ov;
    }
  }
}

// ---------- host ----------
extern "C" void kernel_launch(void* const* d_in, const int* in_sizes, int n_in,
                              void* d_out, int out_size, void* d_ws, size_t ws_size,
                              hipStream_t stream) {
  (void)in_sizes; (void)n_in; (void)out_size; (void)ws_size;
  const float* x   = (const float*)d_in[0];
  const float* g1  = (const float*)d_in[1];
  const float* s1  = (const float*)d_in[2];
  const float* Wq  = (const float*)d_in[3];
  const float* Wk  = (const float*)d_in[4];
  const float* Wv  = (const float*)d_in[5];
  const float* Wo  = (const float*)d_in[6];
  const float* bo  = (const float*)d_in[7];
  const float* g2  = (const float*)d_in[8];
  const float* s2  = (const float*)d_in[9];
  const float* W1  = (const float*)d_in[10];
  const float* b1  = (const float*)d_in[11];
  const float* W2  = (const float*)d_in[12];
  const float* b2  = (const float*)d_in[13];
  float* out = (float*)d_out;
  char* ws = (char*)d_ws;
  const size_t MB = 1024 * 1024;

  u16* wqkvT = (u16*)(ws + 0 * MB);   // 6 MB contiguous (wq/wk/wv), then wo
  u16* woT = (u16*)(ws + 6 * MB);
  u16* w1T = (u16*)(ws + 8 * MB);     // 8 MB  [4096,1024]
  u16* w2T = (u16*)(ws + 16 * MB);    // 8 MB  [1024,4096]
  u16* x1  = (u16*)(ws + 24 * MB);    // 16 MB
  u16* qb  = (u16*)(ws + 40 * MB);    // 16 MB
  u16* kb  = (u16*)(ws + 56 * MB);    // 16 MB
  u16* vb  = (u16*)(ws + 72 * MB);    // 16 MB
  u16* hb  = (u16*)(ws + 24 * MB);    // 64 MB, aliases x1/q/k/v (dead by MLP1)
  u16* zb  = (u16*)(ws + 88 * MB);    // 16 MB
  u16* y1  = (u16*)(ws + 88 * MB);    // 16 MB, aliases zb (dead after Wo proj)
  u16* yb  = (u16*)(ws + 104 * MB);   // 16 MB  bf16 y  -> total 120 MB

  // 1. weight convert + transpose
  wconv4_kernel<<<dim3(32, 32, 4), 256, 0, stream>>>(Wq, Wk, Wv, Wo, wqkvT);
  wconv_kernel<<<dim3(128, 32), 256, 0, stream>>>(W1, w1T, 1024, 4096);
  wconv_kernel<<<dim3(32, 128), 256, 0, stream>>>(W2, w2T, 4096, 1024);
  // 2. LN1
  ln_kernel<<<NROW, 256, 0, stream>>>(x, g1, s1, x1);
  // 3. QKV projections — single z-batched launch (z-major == sequential GEMMs)
  gemm64_qkv3<<<dim3(64, 8, 3), 256, 0, stream>>>(x1, wqkvT, qb, kb, vb, 1024);
  // 4. attention
  attn_kernel<<<dim3(8, 128), 256, 0, stream>>>(qb, kb, vb, zb);
  // 5. output projection + residual -> bf16 y (BK=64)
  gemm64<MODE_YRES><<<dim3(64, 8), 256, 0, stream>>>(zb, woT, bo, x, yb, NROW, 1024, 1024);
  // 6. LN2 (bf16 input)
  ln_bf16_kernel<<<NROW, 256, 0, stream>>>(yb, g2, s2, y1);
  // 7. MLP up + GELU — 256^2 tile (best-measured total: r13 = 350.6 µs)
  gemm256<MODE_GELU><<<dim3(32, 16), 512, 0, stream>>>(y1, w1T, b1, nullptr,
                                                       hb, NROW, 4096, 1024);
  // 8. MLP down + bias + bf16-y residual -> fp32 out (BK=64)
  gemm64<MODE_OUT><<<dim3(64, 8), 256, 0, stream>>>(hb, w2T, b2, (const float*)yb,
                                                    out, NROW, 1024, 4096);
}

// Round 16
// 349.699 us; speedup vs baseline: 1.0509x; 1.0243x over previous
//
#include <hip/hip_runtime.h>

typedef unsigned short u16;
typedef __bf16 bf16x8 __attribute__((ext_vector_type(8)));
typedef float f32x4 __attribute__((ext_vector_type(4)));

#define D_MODEL 1024
#define NHEAD 16
#define DHEAD 64
#define BATCH 8
#define SEQ 1024
#define NROW 8192   // BATCH*SEQ

// ---------- helpers ----------
__device__ __forceinline__ u16 f2bf(float f) {
  union { float f; unsigned int u; } a; a.f = f;
  unsigned int u = a.u;
  return (u16)((u + 0x7fffu + ((u >> 16) & 1u)) >> 16);
}

__device__ __forceinline__ float bf2f(u16 b) {
  union { unsigned int u; float f; } a; a.u = ((unsigned int)b) << 16;
  return a.f;
}

// gelu_tanh(x) == x * sigmoid(2*c*(x+0.044715x^3)); single v_exp_f32, NaN-safe.
__device__ __forceinline__ float gelu_f(float x) {
  float y = 0.79788456080286535588f * (x + 0.044715f * x * x * x);
  return x / (1.0f + __expf(-2.0f * y));
}

__device__ __forceinline__ void async16(const void* gsrc, void* ldst) {
  __builtin_amdgcn_global_load_lds((__attribute__((address_space(1))) void*)gsrc,
                                   (__attribute__((address_space(3))) void*)ldst,
                                   16, 0, 0);
}

// ---------- 4x weight fp32 [1024,1024] -> bf16 W^T, z-indexed ----------
__global__ __launch_bounds__(256)
void wconv4_kernel(const float* __restrict__ Wa, const float* __restrict__ Wb,
                   const float* __restrict__ Wc, const float* __restrict__ Wd,
                   u16* __restrict__ WT) {
  const float* Ws[4] = {Wa, Wb, Wc, Wd};
  const float* W = Ws[blockIdx.z];
  u16* dst = WT + (size_t)blockIdx.z * 1024 * 1024;
  __shared__ float tile[32][33];
  const int tx = threadIdx.x & 31, ty = threadIdx.x >> 5;
  const int n0 = blockIdx.x * 32, k0 = blockIdx.y * 32;
#pragma unroll
  for (int r = 0; r < 4; ++r)
    tile[ty + r * 8][tx] = W[(size_t)(k0 + ty + r * 8) * 1024 + n0 + tx];
  __syncthreads();
#pragma unroll
  for (int r = 0; r < 4; ++r)
    dst[(size_t)(n0 + ty + r * 8) * 1024 + k0 + tx] = f2bf(tile[tx][ty + r * 8]);
}

// ---------- weight fp32 [K,N] -> bf16 W^T [N,K] ----------
__global__ __launch_bounds__(256)
void wconv_kernel(const float* __restrict__ W, u16* __restrict__ WT, int K, int N) {
  __shared__ float tile[32][33];
  const int tx = threadIdx.x & 31, ty = threadIdx.x >> 5;
  const int n0 = blockIdx.x * 32, k0 = blockIdx.y * 32;
#pragma unroll
  for (int r = 0; r < 4; ++r)
    tile[ty + r * 8][tx] = W[(size_t)(k0 + ty + r * 8) * N + n0 + tx];
  __syncthreads();
#pragma unroll
  for (int r = 0; r < 4; ++r)
    WT[(size_t)(n0 + ty + r * 8) * K + k0 + tx] = f2bf(tile[tx][ty + r * 8]);
}

// ---------- layernorm fp32 -> bf16 ----------
__global__ __launch_bounds__(256)
void ln_kernel(const float* __restrict__ x, const float* __restrict__ gamma,
               const float* __restrict__ beta, u16* __restrict__ out) {
  const int row = blockIdx.x, t = threadIdx.x;
  const float4 v = ((const float4*)(x + (size_t)row * D_MODEL))[t];
  float s  = v.x + v.y + v.z + v.w;
  float s2 = v.x * v.x + v.y * v.y + v.z * v.z + v.w * v.w;
#pragma unroll
  for (int off = 32; off >= 1; off >>= 1) {
    s  += __shfl_down(s, off);
    s2 += __shfl_down(s2, off);
  }
  __shared__ float red[8];
  const int w = t >> 6, l = t & 63;
  if (l == 0) { red[w] = s; red[4 + w] = s2; }
  __syncthreads();
  s  = red[0] + red[1] + red[2] + red[3];
  s2 = red[4] + red[5] + red[6] + red[7];
  const float mean = s * (1.0f / D_MODEL);
  const float var  = s2 * (1.0f / D_MODEL) - mean * mean;
  const float inv  = rsqrtf(var + 1e-5f);
  const float4 ga = ((const float4*)gamma)[t];
  const float4 be = ((const float4*)beta)[t];
  ushort4 ov;
  ov.x = f2bf((v.x - mean) * inv * ga.x + be.x);
  ov.y = f2bf((v.y - mean) * inv * ga.y + be.y);
  ov.z = f2bf((v.z - mean) * inv * ga.z + be.z);
  ov.w = f2bf((v.w - mean) * inv * ga.w + be.w);
  ((ushort4*)out)[(size_t)row * 256 + t] = ov;
}

// ---------- layernorm bf16 -> bf16 ----------
__global__ __launch_bounds__(256)
void ln_bf16_kernel(const u16* __restrict__ x, const float* __restrict__ gamma,
                    const float* __restrict__ beta, u16* __restrict__ out) {
  const int row = blockIdx.x, t = threadIdx.x;
  const ushort4 bv = ((const ushort4*)(x + (size_t)row * D_MODEL))[t];
  float4 v;
  v.x = bf2f(bv.x); v.y = bf2f(bv.y); v.z = bf2f(bv.z); v.w = bf2f(bv.w);
  float s  = v.x + v.y + v.z + v.w;
  float s2 = v.x * v.x + v.y * v.y + v.z * v.z + v.w * v.w;
#pragma unroll
  for (int off = 32; off >= 1; off >>= 1) {
    s  += __shfl_down(s, off);
    s2 += __shfl_down(s2, off);
  }
  __shared__ float red[8];
  const int w = t >> 6, l = t & 63;
  if (l == 0) { red[w] = s; red[4 + w] = s2; }
  __syncthreads();
  s  = red[0] + red[1] + red[2] + red[3];
  s2 = red[4] + red[5] + red[6] + red[7];
  const float mean = s * (1.0f / D_MODEL);
  const float var  = s2 * (1.0f / D_MODEL) - mean * mean;
  const float inv  = rsqrtf(var + 1e-5f);
  const float4 ga = ((const float4*)gamma)[t];
  const float4 be = ((const float4*)beta)[t];
  ushort4 ov;
  ov.x = f2bf((v.x - mean) * inv * ga.x + be.x);
  ov.y = f2bf((v.y - mean) * inv * ga.y + be.y);
  ov.z = f2bf((v.z - mean) * inv * ga.z + be.z);
  ov.w = f2bf((v.w - mean) * inv * ga.w + be.w);
  ((ushort4*)out)[(size_t)row * 256 + t] = ov;
}

#define MODE_QK 0
#define MODE_VT 1
#define MODE_YRES 2   // bf16 y = v + bias + f32 resid
#define MODE_GELU 3
#define MODE_OUT 4    // f32 out = v + bias + bf16 resid

// ---------- epilogue for 128^2-tile GEMM ----------
template <int MODE>
__device__ __forceinline__ void gemm_epilogue(f32x4 (&acc)[4][4], int bm, int bn,
                                              int wr, int wc, int c, int g,
                                              const float* bias, const float* resid,
                                              void* outp, int N) {
#pragma unroll
  for (int m = 0; m < 4; ++m) {
    const int r0 = bm * 128 + wr * 64 + m * 16 + g * 4;
#pragma unroll
    for (int n = 0; n < 4; ++n) {
      const int cc = bn * 128 + wc * 64 + n * 16 + c;
#pragma unroll
      for (int i = 0; i < 4; ++i) {
        const int r = r0 + i;
        const float v = acc[m][n][i];
        if constexpr (MODE == MODE_QK) {
          ((u16*)outp)[(((size_t)(r >> 10) * NHEAD + (cc >> 6)) * SEQ + (r & 1023)) * DHEAD + (cc & 63)] = f2bf(v);
        } else if constexpr (MODE == MODE_VT) {
          ((u16*)outp)[(((size_t)(r >> 10) * NHEAD + (cc >> 6)) * DHEAD + (cc & 63)) * SEQ + (r & 1023)] = f2bf(v);
        } else if constexpr (MODE == MODE_YRES) {
          const size_t idx = (size_t)r * N + cc;
          ((u16*)outp)[idx] = f2bf(v + bias[cc] + resid[idx]);
        } else if constexpr (MODE == MODE_OUT) {
          const size_t idx = (size_t)r * N + cc;
          ((float*)outp)[idx] = v + bias[cc] + bf2f(((const u16*)resid)[idx]);
        } else {
          const size_t idx = (size_t)r * N + cc;
          ((u16*)outp)[idx] = f2bf(gelu_f(v + bias[cc]));
        }
      }
    }
  }
}

// ---------- 2-phase GEMM, 128^2 tile, BK=64 (grid-limited GEMMs) ----------
template <int MODE>
__global__ __launch_bounds__(256, 2)
void gemm64(const u16* __restrict__ A, const u16* __restrict__ BT,
            const float* __restrict__ bias, const float* __restrict__ resid,
            void* __restrict__ outp, int M, int N, int K) {
  __shared__ u16 sA[2][128 * 64];
  __shared__ u16 sB[2][128 * 64];
  const int t = threadIdx.x;
  const int w = t >> 6, l = t & 63;
  const int c = l & 15, g = l >> 4;
  const int wr = w >> 1, wc = w & 1;
  const int bm = blockIdx.x, bn = blockIdx.y;

  f32x4 acc[4][4] = {};

  const char* Ab = (const char*)(A + (size_t)bm * 128 * K);
  const char* Bb = (const char*)(BT + (size_t)bn * 128 * K);
  const size_t ldb = (size_t)K * 2;

  int soff[4];
#pragma unroll
  for (int i = 0; i < 4; ++i) {
    const int o = i * 256 + t, row = o >> 3, ch = (o & 7) ^ (row & 7);
    soff[i] = row * (int)ldb + ch * 16;
  }

  auto stage = [&](int buf, int k0) {
    const int kb = k0 * 2;
#pragma unroll
    for (int i = 0; i < 4; ++i) {
      async16(Ab + (size_t)(soff[i] + kb), (char*)sA[buf] + (i * 256 + t) * 16);
      async16(Bb + (size_t)(soff[i] + kb), (char*)sB[buf] + (i * 256 + t) * 16);
    }
  };

  stage(0, 0);
  asm volatile("s_waitcnt vmcnt(0)" ::: "memory");
  __builtin_amdgcn_s_barrier();

  const int nt = K >> 6;
  for (int it = 0; it < nt; ++it) {
    const int cur = it & 1;
    if (it + 1 < nt) stage(cur ^ 1, (it + 1) << 6);
    bf16x8 af[4][2], bfr[4][2];
#pragma unroll
    for (int m = 0; m < 4; ++m) {
      const int row = wr * 64 + m * 16 + c;
#pragma unroll
      for (int ks = 0; ks < 2; ++ks)
        af[m][ks] = *(const bf16x8*)((const char*)sA[cur] + row * 128 + (((ks << 2) + g) ^ (row & 7)) * 16);
    }
#pragma unroll
    for (int n = 0; n < 4; ++n) {
      const int row = wc * 64 + n * 16 + c;
#pragma unroll
      for (int ks = 0; ks < 2; ++ks)
        bfr[n][ks] = *(const bf16x8*)((const char*)sB[cur] + row * 128 + (((ks << 2) + g) ^ (row & 7)) * 16);
    }
#pragma unroll
    for (int ks = 0; ks < 2; ++ks)
#pragma unroll
      for (int m = 0; m < 4; ++m)
#pragma unroll
        for (int n = 0; n < 4; ++n)
          acc[m][n] = __builtin_amdgcn_mfma_f32_16x16x32_bf16(af[m][ks], bfr[n][ks], acc[m][n], 0, 0, 0);
    asm volatile("s_waitcnt vmcnt(0)" ::: "memory");
    __builtin_amdgcn_s_barrier();
  }

  gemm_epilogue<MODE>(acc, bm, bn, wr, wc, c, g, bias, resid, outp, N);
}

// ---------- 2-phase GEMM, 256^2 tile, BK=64, 8 waves (MLP1; best-measured) ----------
template <int MODE>
__global__ __launch_bounds__(512, 2)
void gemm256(const u16* __restrict__ A, const u16* __restrict__ BT,
             const float* __restrict__ bias, const float* __restrict__ resid,
             void* __restrict__ outp, int M, int N, int K) {
  __shared__ u16 sA[2][256 * 64];   // 32 KB each
  __shared__ u16 sB[2][256 * 64];
  const int t = threadIdx.x;
  const int w = t >> 6, l = t & 63;
  const int c = l & 15, g = l >> 4;
  const int wr = w >> 2, wc = w & 3;
  const int bm = blockIdx.x, bn = blockIdx.y;

  f32x4 acc[8][4] = {};

  const char* Ab = (const char*)(A + (size_t)bm * 256 * K);
  const char* Bb = (const char*)(BT + (size_t)bn * 256 * K);
  const size_t ldb = (size_t)K * 2;

  int soff[4];
#pragma unroll
  for (int i = 0; i < 4; ++i) {
    const int o = i * 512 + t, row = o >> 3, ch = (o & 7) ^ (row & 7);
    soff[i] = row * (int)ldb + ch * 16;
  }

  auto stage = [&](int buf, int k0) {
    const int kb = k0 * 2;
#pragma unroll
    for (int i = 0; i < 4; ++i) {
      async16(Ab + (size_t)(soff[i] + kb), (char*)sA[buf] + (i * 512 + t) * 16);
      async16(Bb + (size_t)(soff[i] + kb), (char*)sB[buf] + (i * 512 + t) * 16);
    }
  };

  stage(0, 0);
  asm volatile("s_waitcnt vmcnt(0)" ::: "memory");
  __builtin_amdgcn_s_barrier();

  const int nt = K >> 6;
  for (int it = 0; it < nt; ++it) {
    const int cur = it & 1;
    if (it + 1 < nt) stage(cur ^ 1, (it + 1) << 6);
    bf16x8 bfr[4][2];
#pragma unroll
    for (int n = 0; n < 4; ++n) {
      const int row = wc * 64 + n * 16 + c;
#pragma unroll
      for (int ks = 0; ks < 2; ++ks)
        bfr[n][ks] = *(const bf16x8*)((const char*)sB[cur] + row * 128 + (((ks << 2) + g) ^ (row & 7)) * 16);
    }
#pragma unroll
    for (int m2 = 0; m2 < 4; ++m2) {
      bf16x8 af2[2][2];
#pragma unroll
      for (int mi = 0; mi < 2; ++mi) {
        const int row = wr * 128 + (m2 * 2 + mi) * 16 + c;
#pragma unroll
        for (int ks = 0; ks < 2; ++ks)
          af2[mi][ks] = *(const bf16x8*)((const char*)sA[cur] + row * 128 + (((ks << 2) + g) ^ (row & 7)) * 16);
      }
#pragma unroll
      for (int ks = 0; ks < 2; ++ks)
#pragma unroll
        for (int mi = 0; mi < 2; ++mi)
#pragma unroll
          for (int n = 0; n < 4; ++n)
            acc[m2 * 2 + mi][n] = __builtin_amdgcn_mfma_f32_16x16x32_bf16(
                af2[mi][ks], bfr[n][ks], acc[m2 * 2 + mi][n], 0, 0, 0);
    }
    asm volatile("s_waitcnt vmcnt(0)" ::: "memory");
    __builtin_amdgcn_s_barrier();
  }

#pragma unroll
  for (int m = 0; m < 8; ++m) {
    const int r0 = bm * 256 + wr * 128 + m * 16 + g * 4;
#pragma unroll
    for (int n = 0; n < 4; ++n) {
      const int cc = bn * 256 + wc * 64 + n * 16 + c;
#pragma unroll
      for (int i = 0; i < 4; ++i) {
        const int r = r0 + i;
        const float v = acc[m][n][i];
        if constexpr (MODE == MODE_YRES) {
          const size_t idx = (size_t)r * N + cc;
          ((u16*)outp)[idx] = f2bf(v + bias[cc] + resid[idx]);
        } else if constexpr (MODE == MODE_OUT) {
          const size_t idx = (size_t)r * N + cc;
          ((float*)outp)[idx] = v + bias[cc] + bf2f(((const u16*)resid)[idx]);
        } else {
          const size_t idx = (size_t)r * N + cc;
          ((u16*)outp)[idx] = f2bf(gelu_f(v + bias[cc]));
        }
      }
    }
  }
}

// ---------- causal flash attention ----------
__global__ __launch_bounds__(256, 3)
void attn_kernel(const u16* __restrict__ q, const u16* __restrict__ k,
                 const u16* __restrict__ vT, u16* __restrict__ z) {
  __shared__ u16 sK[2][64 * 64];
  __shared__ u16 sV[2][64 * 64];
  __shared__ u16 pb[4][32 * 64];

  const int t = threadIdx.x, w = t >> 6, l = t & 63;
  const int c = l & 15, g = l >> 4;
  const int bh = blockIdx.y;
  const int qb0 = blockIdx.x * 128;
  const int qw0 = qb0 + w * 32;

  const u16* qbase = q  + (size_t)bh * SEQ * DHEAD;
  const u16* kbase = k  + (size_t)bh * SEQ * DHEAD;
  const u16* vbase = vT + (size_t)bh * DHEAD * SEQ;

  bf16x8 qf[2][2];
#pragma unroll
  for (int j = 0; j < 2; ++j)
#pragma unroll
    for (int hh = 0; hh < 2; ++hh)
      qf[j][hh] = *(const bf16x8*)&qbase[(size_t)(qw0 + j * 16 + c) * DHEAD + hh * 32 + g * 8];

  f32x4 o[4][2] = {};
  float m[2]  = {-3.0e38f, -3.0e38f};
  float ls[2] = {0.0f, 0.0f};

  const int r8 = l >> 3, ch = l & 7;
  const int sw16 = (ch ^ r8) * 16;

  auto stage = [&](int buf, int kt) {
    const int kb0 = kt * 64;
#pragma unroll
    for (int i = 0; i < 2; ++i) {
      const int row = w * 8 + i * 32 + r8;
      async16((const char*)kbase + (size_t)(kb0 + row) * 128 + sw16,
              (char*)sK[buf] + w * 1024 + i * 4096);
      async16((const char*)vbase + (size_t)row * (SEQ * 2) + (size_t)kb0 * 2 + sw16,
              (char*)sV[buf] + w * 1024 + i * 4096);
    }
  };

  const int nkt = blockIdx.x * 2 + 2;
  stage(0, 0);

  for (int kt = 0; kt < nkt; ++kt) {
    const int cur = kt & 1;
    if (kt + 1 < nkt) {
      stage(cur ^ 1, kt + 1);
      asm volatile("s_waitcnt vmcnt(4)" ::: "memory");
    } else {
      asm volatile("s_waitcnt vmcnt(0)" ::: "memory");
    }
    __builtin_amdgcn_s_barrier();

    const int kb0 = kt * 64;
    if (kb0 < qw0 + 32) {
      const u16* sKc = sK[cur];
      const u16* sVc = sV[cur];
      const int cx = c & 7;

      f32x4 st[4][2];
#pragma unroll
      for (int s = 0; s < 4; ++s) {
        const int row = s * 16 + c;
        bf16x8 kf0 = *(const bf16x8*)&sKc[row * 64 + ((0 + g) ^ cx) * 8];
        bf16x8 kf1 = *(const bf16x8*)&sKc[row * 64 + ((4 + g) ^ cx) * 8];
#pragma unroll
        for (int j = 0; j < 2; ++j) {
          f32x4 z4 = {};
          z4 = __builtin_amdgcn_mfma_f32_16x16x32_bf16(kf0, qf[j][0], z4, 0, 0, 0);
          z4 = __builtin_amdgcn_mfma_f32_16x16x32_bf16(kf1, qf[j][1], z4, 0, 0, 0);
          st[s][j] = z4;
        }
      }

      const bool full = (kb0 + 64 <= qw0 + 1);
      float tmax[2] = {-3.0e38f, -3.0e38f};
#pragma unroll
      for (int s = 0; s < 4; ++s)
#pragma unroll
        for (int j = 0; j < 2; ++j)
#pragma unroll
          for (int i = 0; i < 4; ++i) {
            float vsc = st[s][j][i] * 0.125f;
            if (!full) {
              const int key = kb0 + s * 16 + g * 4 + i;
              vsc = (key <= qw0 + j * 16 + c) ? vsc : -1.0e30f;
            }
            st[s][j][i] = vsc;
            tmax[j] = fmaxf(tmax[j], vsc);
          }
#pragma unroll
      for (int j = 0; j < 2; ++j) {
        tmax[j] = fmaxf(tmax[j], __shfl_xor(tmax[j], 16));
        tmax[j] = fmaxf(tmax[j], __shfl_xor(tmax[j], 32));
      }
      float mnew[2], sc[2], psum[2];
#pragma unroll
      for (int j = 0; j < 2; ++j) {
        mnew[j] = fmaxf(m[j], tmax[j]);
        sc[j]   = __expf(m[j] - mnew[j]);
        psum[j] = 0.0f;
      }
#pragma unroll
      for (int s = 0; s < 4; ++s)
#pragma unroll
        for (int j = 0; j < 2; ++j)
#pragma unroll
          for (int i = 0; i < 4; ++i) {
            const float pv = __expf(st[s][j][i] - mnew[j]);
            st[s][j][i] = pv;
            psum[j] += pv;
          }
#pragma unroll
      for (int j = 0; j < 2; ++j) {
        psum[j] += __shfl_xor(psum[j], 16);
        psum[j] += __shfl_xor(psum[j], 32);
        ls[j] = ls[j] * sc[j] + psum[j];
        m[j]  = mnew[j];
#pragma unroll
        for (int d = 0; d < 4; ++d) o[d][j] = o[d][j] * sc[j];
      }

      u16* pw = pb[w];
#pragma unroll
      for (int s = 0; s < 4; ++s)
#pragma unroll
        for (int j = 0; j < 2; ++j) {
          const int row = j * 16 + c;
          const int swz = (s * 2 + (g >> 1)) ^ cx;
          ushort4 pv4;
          pv4.x = f2bf(st[s][j][0]); pv4.y = f2bf(st[s][j][1]);
          pv4.z = f2bf(st[s][j][2]); pv4.w = f2bf(st[s][j][3]);
          *(ushort4*)&pw[row * 64 + swz * 8 + (g & 1) * 4] = pv4;
        }

      bf16x8 pf[2][2];
#pragma unroll
      for (int j = 0; j < 2; ++j)
#pragma unroll
        for (int ks = 0; ks < 2; ++ks)
          pf[j][ks] = *(const bf16x8*)&pw[(j * 16 + c) * 64 + ((ks * 4 + g) ^ cx) * 8];

#pragma unroll
      for (int d = 0; d < 4; ++d) {
        const int vrow = d * 16 + c;
#pragma unroll
        for (int ks = 0; ks < 2; ++ks) {
          bf16x8 vf = *(const bf16x8*)&sVc[vrow * 64 + ((ks * 4 + g) ^ cx) * 8];
#pragma unroll
          for (int j = 0; j < 2; ++j)
            o[d][j] = __builtin_amdgcn_mfma_f32_16x16x32_bf16(vf, pf[j][ks], o[d][j], 0, 0, 0);
        }
      }
    }
    __builtin_amdgcn_s_barrier();
  }

  const int b = bh >> 4, h = bh & 15;
#pragma unroll
  for (int j = 0; j < 2; ++j) {
    const float inv = 1.0f / ls[j];
    const int qrow = qw0 + j * 16 + c;
    u16* zr = z + ((size_t)b * SEQ + qrow) * D_MODEL + h * DHEAD;
#pragma unroll
    for (int d = 0; d < 4; ++d) {
      ushort4 ov;
      ov.x = f2bf(o[d][j][0] * inv); ov.y = f2bf(o[d][j][1] * inv);
      ov.z = f2bf(o[d][j][2] * inv); ov.w = f2bf(o[d][j][3] * inv);
      *(ushort4*)&zr[d * 16 + g * 4] = ov;
    }
  }
}

// ---------- host ----------
extern "C" void kernel_launch(void* const* d_in, const int* in_sizes, int n_in,
                              void* d_out, int out_size, void* d_ws, size_t ws_size,
                              hipStream_t stream) {
  (void)in_sizes; (void)n_in; (void)out_size; (void)ws_size;
  const float* x   = (const float*)d_in[0];
  const float* g1  = (const float*)d_in[1];
  const float* s1  = (const float*)d_in[2];
  const float* Wq  = (const float*)d_in[3];
  const float* Wk  = (const float*)d_in[4];
  const float* Wv  = (const float*)d_in[5];
  const float* Wo  = (const float*)d_in[6];
  const float* bo  = (const float*)d_in[7];
  const float* g2  = (const float*)d_in[8];
  const float* s2  = (const float*)d_in[9];
  const float* W1  = (const float*)d_in[10];
  const float* b1  = (const float*)d_in[11];
  const float* W2  = (const float*)d_in[12];
  const float* b2  = (const float*)d_in[13];
  float* out = (float*)d_out;
  char* ws = (char*)d_ws;
  const size_t MB = 1024 * 1024;

  u16* wqT = (u16*)(ws + 0 * MB);     // 2 MB (wq/wk/wv/wo contiguous)
  u16* wkT = (u16*)(ws + 2 * MB);
  u16* wvT = (u16*)(ws + 4 * MB);
  u16* woT = (u16*)(ws + 6 * MB);
  u16* w1T = (u16*)(ws + 8 * MB);     // 8 MB  [4096,1024]
  u16* w2T = (u16*)(ws + 16 * MB);    // 8 MB  [1024,4096]
  u16* x1  = (u16*)(ws + 24 * MB);    // 16 MB
  u16* qb  = (u16*)(ws + 40 * MB);    // 16 MB
  u16* kb  = (u16*)(ws + 56 * MB);    // 16 MB
  u16* vb  = (u16*)(ws + 72 * MB);    // 16 MB
  u16* hb  = (u16*)(ws + 24 * MB);    // 64 MB, aliases x1/q/k/v (dead by MLP1)
  u16* zb  = (u16*)(ws + 88 * MB);    // 16 MB
  u16* y1  = (u16*)(ws + 88 * MB);    // 16 MB, aliases zb (dead after Wo proj)
  u16* yb  = (u16*)(ws + 104 * MB);   // 16 MB  bf16 y  -> total 120 MB

  // 1. weight convert + transpose
  wconv4_kernel<<<dim3(32, 32, 4), 256, 0, stream>>>(Wq, Wk, Wv, Wo, wqT);
  wconv_kernel<<<dim3(128, 32), 256, 0, stream>>>(W1, w1T, 1024, 4096);
  wconv_kernel<<<dim3(32, 128), 256, 0, stream>>>(W2, w2T, 4096, 1024);
  // 2. LN1
  ln_kernel<<<NROW, 256, 0, stream>>>(x, g1, s1, x1);
  // 3. QKV projections — separate launches (batching diluted L2, r15)
  gemm64<MODE_QK><<<dim3(64, 8), 256, 0, stream>>>(x1, wqT, nullptr, nullptr, qb, NROW, 1024, 1024);
  gemm64<MODE_QK><<<dim3(64, 8), 256, 0, stream>>>(x1, wkT, nullptr, nullptr, kb, NROW, 1024, 1024);
  gemm64<MODE_VT><<<dim3(64, 8), 256, 0, stream>>>(x1, wvT, nullptr, nullptr, vb, NROW, 1024, 1024);
  // 4. attention
  attn_kernel<<<dim3(8, 128), 256, 0, stream>>>(qb, kb, vb, zb);
  // 5. output projection + residual -> bf16 y (BK=64)
  gemm64<MODE_YRES><<<dim3(64, 8), 256, 0, stream>>>(zb, woT, bo, x, yb, NROW, 1024, 1024);
  // 6. LN2 (bf16 input)
  ln_bf16_kernel<<<NROW, 256, 0, stream>>>(yb, g2, s2, y1);
  // 7. MLP up + GELU — 256^2 tile (best-measured total: r13 = 350.6 µs)
  gemm256<MODE_GELU><<<dim3(32, 16), 512, 0, stream>>>(y1, w1T, b1, nullptr,
                                                       hb, NROW, 4096, 1024);
  // 8. MLP down + bias + bf16-y residual -> fp32 out (BK=64)
  gemm64<MODE_OUT><<<dim3(64, 8), 256, 0, stream>>>(hb, w2T, b2, (const float*)yb,
                                                    out, NROW, 1024, 4096);
}